// Round 6
// baseline (85.427 us; speedup 1.0000x reference)
//
#include <hip/hip_runtime.h>
#include <math.h>

// ---------------------------------------------------------------------------
// RegressionLoss: chamfer(32x32 shape pairs of 256 3D pts) -> softmax vs
// normalized-embedding inner-product softmax -> mean |p_hat - p|.
// Inputs: d_in[0] = embeddings (64x512 f32), d_in[1] = xyz (64x256x3 f32).
// Output: d_out[0] single f32.
//
// R6: single-dispatch fusion of R3 (best so far, 66.2us). R4/R5 post-mortem:
// the chamfer loop is latency/occupancy-bound, not LDS-issue-bound (halving
// LDS instrs with 2x fewer blocks REGRESSED). Keep R3's 992 chamfer +
// 32 dot-row blocks = 1024 blocks = 4/CU, and eliminate the serial 1-block
// finish dispatch: last block (device-scope atomic counter, zeroed by a
// 4-byte hipMemsetAsync before launch) runs the epilogue inline.
// ---------------------------------------------------------------------------

typedef float f32x2 __attribute__((ext_vector_type(2)));

__device__ __forceinline__ float waveReduceSum64(float v) {
    #pragma unroll
    for (int m = 32; m > 0; m >>= 1) v += __shfl_xor(v, m, 64);
    return v;
}

// blocks [0,992): directional chamfer half. pb=b>>1 indexes strict upper
//   triangle (i<j) of 32; dir=b&1. cdHalf[b] = mean_p min_q d2.
// blocks [992,1024): dot row i=b-992 -> dots[i*32+j].
// Last block to finish runs the softmax epilogue.
__global__ __launch_bounds__(256) void fused_kernel(const float* __restrict__ emb,
                                                    const float* __restrict__ xyz,
                                                    float* __restrict__ cdHalf,
                                                    float* __restrict__ dots,
                                                    unsigned int* __restrict__ ctr,
                                                    float* __restrict__ out) {
    const int t = threadIdx.x;
    const int b = blockIdx.x;

    __shared__ __align__(16) float S[3 * 256];
    __shared__ float red[4];
    __shared__ int lastFlag;
    float* Sx = S;
    float* Sy = S + 256;
    float* Sz = S + 512;

    if (b < 992) {
        const int pb  = b >> 1;
        const int dir = b & 1;
        // strict-upper-triangle decode: row i has (31-i) entries
        int i = 0, rem = pb;
        while (rem >= (31 - i)) { rem -= (31 - i); ++i; }
        const int j = i + 1 + rem;

        const int outer = dir ? j : i;
        const int inner = dir ? i : j;

        const float* Po = xyz + (32 + outer) * 768;   // shapes = xyz[32:]
        const float* Pi = xyz + (32 + inner) * 768;

        const float ix = Pi[3*t], iy = Pi[3*t+1], iz = Pi[3*t+2];
        Sx[t] = ix; Sy[t] = iy; Sz[t] = iz;
        const float px = Po[3*t], py = Po[3*t+1], pz = Po[3*t+2];
        __syncthreads();

        const f32x2 Px = {px, px}, Py = {py, py}, Pz = {pz, pz};
        float m0 = 3.4e38f;

        #pragma unroll 4
        for (int s = 0; s < 256; s += 4) {
            const float4 vx = *(const float4*)&Sx[s];   // broadcast b128
            const float4 vy = *(const float4*)&Sy[s];
            const float4 vz = *(const float4*)&Sz[s];
            {   // s, s+1
                const f32x2 bx = {vx.x, vx.y}, by = {vy.x, vy.y}, bz = {vz.x, vz.y};
                f32x2 dx = Px - bx, dy = Py - by, dz = Pz - bz;
                f32x2 d = dx*dx + dy*dy + dz*dz;
                m0 = fminf(m0, fminf(d.x, d.y));   // v_min3 bait
            }
            {   // s+2, s+3
                const f32x2 bx = {vx.z, vx.w}, by = {vy.z, vy.w}, bz = {vz.z, vz.w};
                f32x2 dx = Px - bx, dy = Py - by, dz = Pz - bz;
                f32x2 d = dx*dx + dy*dy + dz*dz;
                m0 = fminf(m0, fminf(d.x, d.y));
            }
        }

        float v = waveReduceSum64(m0);
        if ((t & 63) == 0) red[t >> 6] = v;
        __syncthreads();
        if (t == 0)
            cdHalf[b] = (red[0] + red[1] + red[2] + red[3]) * (1.0f / 256.0f);
    } else {
        const int i = b - 992;    // sketch row 0..31
        float* rowi = S;          // 512 floats
        const float* Ei = emb + i * 512;
        rowi[t]       = Ei[t];
        rowi[t + 256] = Ei[t + 256];
        __syncthreads();

        const int w    = t >> 6;
        const int lane = t & 63;

        float ni = 0.0f;
        #pragma unroll
        for (int m = 0; m < 8; ++m) { float a = rowi[lane + 64*m]; ni += a*a; }
        ni = waveReduceSum64(ni);

        // 4 waves x 8 shape columns each
        for (int j = w; j < 32; j += 4) {
            const float* Ej = emb + (32 + j) * 512;
            float dot = 0.0f, nj = 0.0f;
            #pragma unroll
            for (int m = 0; m < 8; ++m) {
                float a  = rowi[lane + 64*m];
                float bv = Ej[lane + 64*m];
                dot += a * bv;
                nj  += bv * bv;
            }
            dot = waveReduceSum64(dot);
            nj  = waveReduceSum64(nj);
            if (lane == 0) dots[i * 32 + j] = dot * rsqrtf(ni * nj);
        }
    }

    // ---- completion count; last block runs the epilogue -------------------
    __syncthreads();                 // all this block's global writes issued
    if (t == 0) {
        __threadfence();             // release: make writes device-visible
        unsigned int old = atomicAdd(ctr, 1u);
        lastFlag = (old == 1023u);
    }
    __syncthreads();
    if (!lastFlag) return;

    __threadfence();                 // acquire side

    const float inv_denom = 1.0f / (2.0f * (0.997f / 3.0f) * (0.997f / 3.0f));
    float acc = 0.0f;

    #pragma unroll
    for (int r = 0; r < 4; ++r) {
        const int idx = r * 256 + t;     // idx = i*32 + j
        const int i = idx >> 5;
        const int j = idx & 31;

        float c;
        if (i == j) {
            c = 0.0f;                    // chamfer(self) == 0
        } else {
            const int a  = min(i, j), bb = max(i, j);
            const int pb = a * 31 - (a * (a - 1)) / 2 + (bb - a - 1);
            float h0 = __hip_atomic_load(&cdHalf[2 * pb],     __ATOMIC_ACQUIRE, __HIP_MEMORY_SCOPE_AGENT);
            float h1 = __hip_atomic_load(&cdHalf[2 * pb + 1], __ATOMIC_ACQUIRE, __HIP_MEMORY_SCOPE_AGENT);
            c = h0 + h1;
        }
        float s = -(c * c) * inv_denom;
        float h = __hip_atomic_load(&dots[idx], __ATOMIC_ACQUIRE, __HIP_MEMORY_SCOPE_AGENT);

        // softmax of s over the 32-wide row segment
        float m1 = s;
        #pragma unroll
        for (int k = 16; k > 0; k >>= 1) m1 = fmaxf(m1, __shfl_xor(m1, k, 32));
        float e1 = expf(s - m1);
        float sum1 = e1;
        #pragma unroll
        for (int k = 16; k > 0; k >>= 1) sum1 += __shfl_xor(sum1, k, 32);
        float p = e1 / sum1;

        // softmax of h over the row segment
        float m2 = h;
        #pragma unroll
        for (int k = 16; k > 0; k >>= 1) m2 = fmaxf(m2, __shfl_xor(m2, k, 32));
        float e2 = expf(h - m2);
        float sum2 = e2;
        #pragma unroll
        for (int k = 16; k > 0; k >>= 1) sum2 += __shfl_xor(sum2, k, 32);
        float ph = e2 / sum2;

        acc += fabsf(ph - p);
    }

    acc = waveReduceSum64(acc);
    __syncthreads();                 // red[] reuse safe
    if ((t & 63) == 0) red[t >> 6] = acc;
    __syncthreads();
    if (t == 0)
        out[0] = (red[0] + red[1] + red[2] + red[3]) * (1.0f / 1024.0f);
}

extern "C" void kernel_launch(void* const* d_in, const int* in_sizes, int n_in,
                              void* d_out, int out_size, void* d_ws, size_t ws_size,
                              hipStream_t stream) {
    const float* emb = (const float*)d_in[0];   // 64 x 512
    const float* xyz = (const float*)d_in[1];   // 64 x 256 x 3
    float* cdHalf = (float*)d_ws;               // 992 directional halves
    float* dots   = cdHalf + 1024;              // 32x32
    unsigned int* ctr = (unsigned int*)((char*)d_ws + 8192);
    float* out    = (float*)d_out;

    hipMemsetAsync(ctr, 0, sizeof(unsigned int), stream);   // counter = 0
    hipLaunchKernelGGL(fused_kernel, dim3(1024), dim3(256), 0, stream,
                       emb, xyz, cdHalf, dots, ctr, out);
}

// Round 7
// 68.913 us; speedup vs baseline: 1.2396x; 1.2396x over previous
//
#include <hip/hip_runtime.h>
#include <math.h>

// ---------------------------------------------------------------------------
// RegressionLoss: chamfer(32x32 shape pairs of 256 3D pts) -> softmax vs
// normalized-embedding inner-product softmax -> mean |p_hat - p|.
// Inputs: d_in[0] = embeddings (64x512 f32), d_in[1] = xyz (64x256x3 f32).
// Output: d_out[0] single f32.
//
// R7: R3 structure (best, 66.2us: 992 directional chamfer + 32 dot rows =
// 1024 blocks, two dispatches -- R6's atomic fusion cost +19us, reverted)
// but with 128-THREAD blocks: each thread owns TWO outer points, so each
// broadcast ds_read_b128 feeds 2x the distance math. Total LDS instrs
// halve (762K -> 381K) at constant VALU, constant 1024-block balance
// (4 blocks/CU, 8 waves/CU). Tests the "LDS RF-write-bound" model that
// R5 couldn't isolate (it also dropped to 2 blocks/CU + serial dots tail).
// ---------------------------------------------------------------------------

typedef float f32x2 __attribute__((ext_vector_type(2)));

__device__ __forceinline__ float waveReduceSum64(float v) {
    #pragma unroll
    for (int m = 32; m > 0; m >>= 1) v += __shfl_xor(v, m, 64);
    return v;
}

// blocks [0,992): directional chamfer half, 128 threads, 2 outer pts/thread.
//   pb=b>>1 indexes strict upper triangle (i<j) of 32; dir=b&1.
//   cdHalf[b] = mean_p min_q ||P_outer[p]-P_inner[q]||^2.
// blocks [992,1024): dot row i=b-992 -> dots[i*32+j].
__global__ __launch_bounds__(128) void pairs_kernel(const float* __restrict__ emb,
                                                    const float* __restrict__ xyz,
                                                    float* __restrict__ cdHalf,
                                                    float* __restrict__ dots) {
    const int t = threadIdx.x;        // 0..127
    const int b = blockIdx.x;

    __shared__ __align__(16) float S[3 * 256];   // inner shape SoA: x,y,z
    __shared__ float red[2];
    float* Sx = S;
    float* Sy = S + 256;
    float* Sz = S + 512;

    if (b < 992) {
        const int pb  = b >> 1;
        const int dir = b & 1;
        // strict-upper-triangle decode: row i has (31-i) entries
        int i = 0, rem = pb;
        while (rem >= (31 - i)) { rem -= (31 - i); ++i; }
        const int j = i + 1 + rem;

        const int outer = dir ? j : i;
        const int inner = dir ? i : j;

        const float* Po = xyz + (32 + outer) * 768;   // shapes = xyz[32:]
        const float* Pi = xyz + (32 + inner) * 768;

        // stage inner shape (256 pts) with 128 threads: 2 pts each
        {
            const int t2 = t + 128;
            Sx[t]  = Pi[3*t+0];   Sy[t]  = Pi[3*t+1];   Sz[t]  = Pi[3*t+2];
            Sx[t2] = Pi[3*t2+0];  Sy[t2] = Pi[3*t2+1];  Sz[t2] = Pi[3*t2+2];
        }
        // my TWO outer points (divergent, coalesced)
        const float pax = Po[3*t+0],       pay = Po[3*t+1],       paz = Po[3*t+2];
        const float pbx = Po[3*(t+128)+0], pby = Po[3*(t+128)+1], pbz = Po[3*(t+128)+2];
        __syncthreads();

        const f32x2 Ax = {pax, pax}, Ay = {pay, pay}, Az = {paz, paz};
        const f32x2 Bx = {pbx, pbx}, By = {pby, pby}, Bz = {pbz, pbz};

        float accA = 3.4e38f, accB = 3.4e38f;

        #pragma unroll 4
        for (int s = 0; s < 256; s += 4) {
            const float4 vx = *(const float4*)&Sx[s];   // broadcast b128
            const float4 vy = *(const float4*)&Sy[s];
            const float4 vz = *(const float4*)&Sz[s];
            {   // inner pts s, s+1
                const f32x2 qx = {vx.x, vx.y}, qy = {vy.x, vy.y}, qz = {vz.x, vz.y};
                f32x2 dax = Ax - qx, day = Ay - qy, daz = Az - qz;
                f32x2 da = dax*dax + day*day + daz*daz;
                accA = fminf(accA, fminf(da.x, da.y));   // v_min3
                f32x2 dbx = Bx - qx, dby = By - qy, dbz = Bz - qz;
                f32x2 db = dbx*dbx + dby*dby + dbz*dbz;
                accB = fminf(accB, fminf(db.x, db.y));
            }
            {   // inner pts s+2, s+3
                const f32x2 qx = {vx.z, vx.w}, qy = {vy.z, vy.w}, qz = {vz.z, vz.w};
                f32x2 dax = Ax - qx, day = Ay - qy, daz = Az - qz;
                f32x2 da = dax*dax + day*day + daz*daz;
                accA = fminf(accA, fminf(da.x, da.y));
                f32x2 dbx = Bx - qx, dby = By - qy, dbz = Bz - qz;
                f32x2 db = dbx*dbx + dby*dby + dbz*dbz;
                accB = fminf(accB, fminf(db.x, db.y));
            }
        }

        // sum over all 256 outer points = sum over threads of (accA + accB)
        float v = waveReduceSum64(accA + accB);
        if ((t & 63) == 0) red[t >> 6] = v;
        __syncthreads();
        if (t == 0)
            cdHalf[b] = (red[0] + red[1]) * (1.0f / 256.0f);
    } else {
        const int i = b - 992;    // sketch row 0..31
        float* rowi = S;          // 512 floats
        const float* Ei = emb + i * 512;
        rowi[t]       = Ei[t];
        rowi[t + 128] = Ei[t + 128];
        rowi[t + 256] = Ei[t + 256];
        rowi[t + 384] = Ei[t + 384];
        __syncthreads();

        const int w    = t >> 6;          // 0..1
        const int lane = t & 63;

        // norm^2 of sketch row i (redundant per wave, cheap)
        float ni = 0.0f;
        #pragma unroll
        for (int m = 0; m < 8; ++m) { float a = rowi[lane + 64*m]; ni += a*a; }
        ni = waveReduceSum64(ni);

        // 2 waves x 16 shape columns each
        for (int j = w; j < 32; j += 2) {
            const float* Ej = emb + (32 + j) * 512;
            float dot = 0.0f, nj = 0.0f;
            #pragma unroll
            for (int m = 0; m < 8; ++m) {
                float a  = rowi[lane + 64*m];
                float bv = Ej[lane + 64*m];
                dot += a * bv;
                nj  += bv * bv;
            }
            dot = waveReduceSum64(dot);
            nj  = waveReduceSum64(nj);
            if (lane == 0) dots[i * 32 + j] = dot * rsqrtf(ni * nj);
        }
    }
}

// 1 block x 1024 threads: assemble cd, softmaxes, mean abs diff
__global__ __launch_bounds__(1024) void finish_kernel(const float* __restrict__ cdHalf,
                                                      const float* __restrict__ dots,
                                                      float* __restrict__ out) {
    const int t = threadIdx.x;   // t = i*32 + j ; width-32 segments == rows
    const int i = t >> 5;
    const int j = t & 31;
    const float inv_denom = 1.0f / (2.0f * (0.997f / 3.0f) * (0.997f / 3.0f));

    float c;
    if (i == j) {
        c = 0.0f;                 // chamfer(self) == 0 (min includes q=p)
    } else {
        const int a  = min(i, j), bb = max(i, j);
        const int pb = a * 31 - (a * (a - 1)) / 2 + (bb - a - 1);
        c = cdHalf[2 * pb] + cdHalf[2 * pb + 1];
    }
    float s = -(c * c) * inv_denom;
    float h = dots[t];

    float m1 = s;
    #pragma unroll
    for (int k = 16; k > 0; k >>= 1) m1 = fmaxf(m1, __shfl_xor(m1, k, 32));
    float e1 = expf(s - m1);
    float sum1 = e1;
    #pragma unroll
    for (int k = 16; k > 0; k >>= 1) sum1 += __shfl_xor(sum1, k, 32);
    float p = e1 / sum1;

    float m2 = h;
    #pragma unroll
    for (int k = 16; k > 0; k >>= 1) m2 = fmaxf(m2, __shfl_xor(m2, k, 32));
    float e2 = expf(h - m2);
    float sum2 = e2;
    #pragma unroll
    for (int k = 16; k > 0; k >>= 1) sum2 += __shfl_xor(sum2, k, 32);
    float ph = e2 / sum2;

    float a = fabsf(ph - p);
    a = waveReduceSum64(a);

    __shared__ float red[16];
    if ((t & 63) == 0) red[t >> 6] = a;
    __syncthreads();
    if (t == 0) {
        float tot = 0.0f;
        #pragma unroll
        for (int k = 0; k < 16; ++k) tot += red[k];
        out[0] = tot * (1.0f / 1024.0f);
    }
}

extern "C" void kernel_launch(void* const* d_in, const int* in_sizes, int n_in,
                              void* d_out, int out_size, void* d_ws, size_t ws_size,
                              hipStream_t stream) {
    const float* emb = (const float*)d_in[0];   // 64 x 512
    const float* xyz = (const float*)d_in[1];   // 64 x 256 x 3
    float* cdHalf = (float*)d_ws;               // 992 directional halves
    float* dots   = cdHalf + 1024;              // 32x32
    float* out    = (float*)d_out;

    hipLaunchKernelGGL(pairs_kernel, dim3(1024), dim3(128), 0, stream, emb, xyz, cdHalf, dots);
    hipLaunchKernelGGL(finish_kernel, dim3(1), dim3(1024), 0, stream, cdHalf, dots, out);
}